// Round 15
// baseline (278.118 us; speedup 1.0000x reference)
//
#include <hip/hip_runtime.h>
#include <hip/hip_bf16.h>
#include <stdint.h>

#define S_LEN 1024
#define B_SZ  4
#define E_SZ  1024
#define H_CNT 16
#define D_HD  64
#define N1    (B_SZ * H_CNT * S_LEN * D_HD)   // 4194304 elements per component
#define WELEM (E_SZ * E_SZ)                   // 1048576

typedef __attribute__((ext_vector_type(8))) short short8;
typedef __attribute__((ext_vector_type(4))) float f32x4;

__device__ __forceinline__ ushort f2bf(float f) {
  union { float f; uint32_t u; } v; v.f = f;
  uint32_t u = v.u;
  uint32_t r = (u + 0x7fffu + ((u >> 16) & 1u)) >> 16;  // RNE
  return (ushort)r;
}
__device__ __forceinline__ short8 pack8(float4 a, float4 b) {
  short8 r;
  r[0] = (short)f2bf(a.x); r[1] = (short)f2bf(a.y);
  r[2] = (short)f2bf(a.z); r[3] = (short)f2bf(a.w);
  r[4] = (short)f2bf(b.x); r[5] = (short)f2bf(b.y);
  r[6] = (short)f2bf(b.z); r[7] = (short)f2bf(b.w);
  return r;
}
static __device__ __forceinline__ f32x4 mfma16(short8 a, short8 b, f32x4 c) {
  return __builtin_amdgcn_mfma_f32_16x16x32_bf16(a, b, c, 0, 0, 0);
}

typedef const __attribute__((address_space(1))) void gv_t;
typedef __attribute__((address_space(3))) void lv_t;
__device__ __forceinline__ void gld16(const void* g, void* l) {
  __builtin_amdgcn_global_load_lds((gv_t*)g, (lv_t*)l, 16, 0, 0);
}

// ---------------------------------------------------------------------------
// Fused cast kernel: 8 weight matrices (4 el/thread) + 3 activation pairs
// (8 el/thread).  blocks [0,8192) = weights; [8192,14336) = activations.
// ---------------------------------------------------------------------------
__global__ __launch_bounds__(256) void cast_all(
    const float* __restrict__ s0, const float* __restrict__ s1,
    const float* __restrict__ s2, const float* __restrict__ s3,
    const float* __restrict__ s4, const float* __restrict__ s5,
    const float* __restrict__ s6, const float* __restrict__ s7,
    ushort* __restrict__ wdst,
    const float* __restrict__ qr, const float* __restrict__ qi,
    const float* __restrict__ kr, const float* __restrict__ ki,
    const float* __restrict__ vr, const float* __restrict__ vi,
    ushort* __restrict__ xq_r, ushort* __restrict__ xq_i,
    ushort* __restrict__ xk_r, ushort* __restrict__ xk_i,
    ushort* __restrict__ xv_r, ushort* __restrict__ xv_i)
{
  int blk = blockIdx.x;
  if (blk < 8192) {
    const size_t i = (size_t)blk * 256 + threadIdx.x;
    const size_t e = i * 4;
    const int which = (int)(e >> 20);
    const size_t off = e & (WELEM - 1);
    const float* s = which < 4
        ? (which < 2 ? (which == 0 ? s0 : s1) : (which == 2 ? s2 : s3))
        : (which < 6 ? (which == 4 ? s4 : s5) : (which == 6 ? s6 : s7));
    const float4 f = *(const float4*)(s + off);
    ushort4 u;
    u.x = f2bf(f.x); u.y = f2bf(f.y); u.z = f2bf(f.z); u.w = f2bf(f.w);
    *(ushort4*)(wdst + e) = u;
    return;
  }
  blk -= 8192;
  const float *xr, *xi; ushort *yr, *yi;
  if      (blk < 2048) { xr = qr; xi = qi; yr = xq_r; yi = xq_i; }
  else if (blk < 4096) { xr = kr; xi = ki; yr = xk_r; yi = xk_i; blk -= 2048; }
  else                 { xr = vr; xi = vi; yr = xv_r; yi = xv_i; blk -= 4096; }
  const size_t e = ((size_t)blk * 256 + threadIdx.x) * 8;
  float4 a = *(const float4*)(xr + e);
  float4 b = *(const float4*)(xr + e + 4);
  *(short8*)(yr + e) = pack8(a, b);
  a = *(const float4*)(xi + e);
  b = *(const float4*)(xi + e + 4);
  *(short8*)(yi + e) = pack8(a, b);
}

// ---------------------------------------------------------------------------
// Unified complex bf16 MFMA GEMM:  Y = (A @ W^T + bias) * scale
// Tile BM=128 x BN=64, BK=64; 256 threads = 4 waves (2x2), wave tile 64x32.
// MODE 0: out bf16 [B,H,S,D]; MODE 1: out bf16 [B,H,D,S]; MODE 2: fp32 [S,B,E,2]
// ---------------------------------------------------------------------------
template<int MODE>
__global__ __launch_bounds__(256) void cgemm(
    const ushort* __restrict__ ar_, const ushort* __restrict__ ai_,
    const ushort* __restrict__ wre, const ushort* __restrict__ wim,
    const float* __restrict__ bre, const float* __restrict__ bim,
    ushort* __restrict__ yr, ushort* __restrict__ yi,
    float* __restrict__ outf, float scale)
{
  __shared__ __align__(16) ushort sAr[128 * 64], sAi[128 * 64];
  __shared__ __align__(16) ushort sBr[64 * 64],  sBi[64 * 64];

  const int tid  = threadIdx.x;
  const int lane = tid & 63;
  const int w    = tid >> 6;
  const int wrow = w >> 1, wcol = w & 1;
  const int fr   = lane & 15, fq = lane >> 4;

  // bijective XCD swizzle over 512 workgroups (512 % 8 == 0)
  const int flat = blockIdx.x + gridDim.x * blockIdx.y;
  const int swz  = (flat & 7) * 64 + (flat >> 3);
  const int n0   = (swz & 15) * 64;    // 16 n-tiles of 64
  const int m0   = (swz >> 4) * 128;   // 32 m-tiles of 128

  const ushort* gbase = (w == 0) ? ar_ : (w == 1) ? ai_ : (w == 2) ? wre : wim;
  char* sbase = (w == 0) ? (char*)sAr : (w == 1) ? (char*)sAi
              : (w == 2) ? (char*)sBr : (char*)sBi;
  const int rbase = (w < 2) ? m0 : n0;
  const int lrow  = lane >> 3;            // 0..7
  const int sch   = (lane & 7) ^ lrow;    // pre-swizzled source chunk
  const ushort* gp0 = gbase + (size_t)(rbase + lrow) * E_SZ + sch * 8;

  f32x4 accR[4][2] = {}, accI[4][2] = {};

  for (int kt = 0; kt < 16; ++kt) {
    const int k0 = kt * 64;
    __syncthreads();   // previous tile fully consumed
    if (w < 2) {
#pragma unroll
      for (int i = 0; i < 16; ++i)
        gld16(gp0 + (size_t)i * 8 * E_SZ + k0, sbase + i * 1024);
    } else {
#pragma unroll
      for (int i = 0; i < 8; ++i)
        gld16(gp0 + (size_t)i * 8 * E_SZ + k0, sbase + i * 1024);
    }
    __syncthreads();   // vmcnt drained by barrier: tile ready

#pragma unroll
    for (int kk = 0; kk < 2; ++kk) {
      short8 a_r[4], a_i[4], a_n[4], b_r[2], b_i[2];
#pragma unroll
      for (int mi = 0; mi < 4; ++mi) {
        const int row = wrow * 64 + mi * 16 + fr;
        const int off = row * 128 + (((kk * 4 + fq) ^ (row & 7)) << 4);
        a_r[mi] = *(const short8*)((const char*)sAr + off);
        a_i[mi] = *(const short8*)((const char*)sAi + off);
        a_n[mi] = a_i[mi] ^ (short)0x8000;
      }
#pragma unroll
      for (int ni = 0; ni < 2; ++ni) {
        const int row = wcol * 32 + ni * 16 + fr;
        const int off = row * 128 + (((kk * 4 + fq) ^ (row & 7)) << 4);
        b_r[ni] = *(const short8*)((const char*)sBr + off);
        b_i[ni] = *(const short8*)((const char*)sBi + off);
      }
      __builtin_amdgcn_s_setprio(1);
#pragma unroll
      for (int mi = 0; mi < 4; ++mi)
#pragma unroll
        for (int ni = 0; ni < 2; ++ni) {
          accR[mi][ni] = mfma16(a_r[mi], b_r[ni], accR[mi][ni]);
          accR[mi][ni] = mfma16(a_n[mi], b_i[ni], accR[mi][ni]);
          accI[mi][ni] = mfma16(a_r[mi], b_i[ni], accI[mi][ni]);
          accI[mi][ni] = mfma16(a_i[mi], b_r[ni], accI[mi][ni]);
        }
      __builtin_amdgcn_s_setprio(0);
    }
  }

  // epilogue: C/D layout col=lane&15, row=(lane>>4)*4+reg
#pragma unroll
  for (int ni = 0; ni < 2; ++ni) {
    const int n = n0 + wcol * 32 + ni * 16 + fr;
    const float bR = bre[n], bI = bim[n];
    const int h = n >> 6, d = n & 63;
#pragma unroll
    for (int mi = 0; mi < 4; ++mi) {
      const int mb = m0 + wrow * 64 + mi * 16 + fq * 4;
#pragma unroll
      for (int q = 0; q < 4; ++q) {
        const int m = mb + q;
        const float vr = (accR[mi][ni][q] + bR) * scale;
        const float vi = (accI[mi][ni][q] + bI) * scale;
        if (MODE == 0) {
          const int s = m >> 2, b = m & 3;   // m = s*B + b
          const size_t o = (((size_t)(b * H_CNT + h) * S_LEN) + s) * D_HD + d;
          yr[o] = f2bf(vr); yi[o] = f2bf(vi);
        } else if (MODE == 1) {
          const int s = m >> 2, b = m & 3;
          const size_t o = (((size_t)(b * H_CNT + h) * D_HD) + d) * S_LEN + s;
          yr[o] = f2bf(vr); yi[o] = f2bf(vi);
        } else {
          const int b = m >> 10, s = m & 1023;  // m = b*S + s
          const size_t o = (((size_t)(s * B_SZ + b) * E_SZ) + n) * 2;
          outf[o] = vr; outf[o + 1] = vi;
        }
      }
    }
  }
}

// ---------------------------------------------------------------------------
// Merged Q+K complex GEMM, XCD-partitioned (proven neutral-to-positive).
// ---------------------------------------------------------------------------
__global__ __launch_bounds__(256) void cgemm_qk(
    const ushort* __restrict__ aQr, const ushort* __restrict__ aQi,
    const ushort* __restrict__ aKr, const ushort* __restrict__ aKi,
    const ushort* __restrict__ wQr, const ushort* __restrict__ wQi,
    const ushort* __restrict__ wKr, const ushort* __restrict__ wKi,
    const float* __restrict__ bQr, const float* __restrict__ bQi,
    const float* __restrict__ bKr, const float* __restrict__ bKi,
    ushort* __restrict__ yQr, ushort* __restrict__ yQi,
    ushort* __restrict__ yKr, ushort* __restrict__ yKi,
    float qscale)
{
  __shared__ __align__(16) ushort sAr[128 * 64], sAi[128 * 64];
  __shared__ __align__(16) ushort sBr[64 * 64],  sBi[64 * 64];

  const int id    = blockIdx.x;          // 0..1023
  const int isKop = (id >> 2) & 1;       // xcd 0-3 -> Q, xcd 4-7 -> K
  const int lid   = ((id >> 3) << 2) | (id & 3);   // 0..511 within op

  const ushort* ar_ = isKop ? aKr : aQr;
  const ushort* ai_ = isKop ? aKi : aQi;
  const ushort* wre = isKop ? wKr : wQr;
  const ushort* wim = isKop ? wKi : wQi;
  const float*  bre = isKop ? bKr : bQr;
  const float*  bim = isKop ? bKi : bQi;
  ushort* yr = isKop ? yKr : yQr;
  ushort* yi = isKop ? yKi : yQi;
  const float scale = isKop ? 1.0f : qscale;

  const int tid  = threadIdx.x;
  const int lane = tid & 63;
  const int w    = tid >> 6;
  const int wrow = w >> 1, wcol = w & 1;
  const int fr   = lane & 15, fq = lane >> 4;

  // bijective locality swizzle over the 4 XCDs of this op (512 blocks)
  const int swz  = (lid & 3) * 128 + (lid >> 2);
  const int n0   = (swz & 15) * 64;
  const int m0   = (swz >> 4) * 128;

  const ushort* gbase = (w == 0) ? ar_ : (w == 1) ? ai_ : (w == 2) ? wre : wim;
  char* sbase = (w == 0) ? (char*)sAr : (w == 1) ? (char*)sAi
              : (w == 2) ? (char*)sBr : (char*)sBi;
  const int rbase = (w < 2) ? m0 : n0;
  const int lrow  = lane >> 3;
  const int sch   = (lane & 7) ^ lrow;
  const ushort* gp0 = gbase + (size_t)(rbase + lrow) * E_SZ + sch * 8;

  f32x4 accR[4][2] = {}, accI[4][2] = {};

  for (int kt = 0; kt < 16; ++kt) {
    const int k0 = kt * 64;
    __syncthreads();
    if (w < 2) {
#pragma unroll
      for (int i = 0; i < 16; ++i)
        gld16(gp0 + (size_t)i * 8 * E_SZ + k0, sbase + i * 1024);
    } else {
#pragma unroll
      for (int i = 0; i < 8; ++i)
        gld16(gp0 + (size_t)i * 8 * E_SZ + k0, sbase + i * 1024);
    }
    __syncthreads();

#pragma unroll
    for (int kk = 0; kk < 2; ++kk) {
      short8 a_r[4], a_i[4], a_n[4], b_r[2], b_i[2];
#pragma unroll
      for (int mi = 0; mi < 4; ++mi) {
        const int row = wrow * 64 + mi * 16 + fr;
        const int off = row * 128 + (((kk * 4 + fq) ^ (row & 7)) << 4);
        a_r[mi] = *(const short8*)((const char*)sAr + off);
        a_i[mi] = *(const short8*)((const char*)sAi + off);
        a_n[mi] = a_i[mi] ^ (short)0x8000;
      }
#pragma unroll
      for (int ni = 0; ni < 2; ++ni) {
        const int row = wcol * 32 + ni * 16 + fr;
        const int off = row * 128 + (((kk * 4 + fq) ^ (row & 7)) << 4);
        b_r[ni] = *(const short8*)((const char*)sBr + off);
        b_i[ni] = *(const short8*)((const char*)sBi + off);
      }
      __builtin_amdgcn_s_setprio(1);
#pragma unroll
      for (int mi = 0; mi < 4; ++mi)
#pragma unroll
        for (int ni = 0; ni < 2; ++ni) {
          accR[mi][ni] = mfma16(a_r[mi], b_r[ni], accR[mi][ni]);
          accR[mi][ni] = mfma16(a_n[mi], b_i[ni], accR[mi][ni]);
          accI[mi][ni] = mfma16(a_r[mi], b_i[ni], accI[mi][ni]);
          accI[mi][ni] = mfma16(a_i[mi], b_r[ni], accI[mi][ni]);
        }
      __builtin_amdgcn_s_setprio(0);
    }
  }

#pragma unroll
  for (int ni = 0; ni < 2; ++ni) {
    const int n = n0 + wcol * 32 + ni * 16 + fr;
    const float bR = bre[n], bI = bim[n];
    const int h = n >> 6, d = n & 63;
#pragma unroll
    for (int mi = 0; mi < 4; ++mi) {
      const int mb = m0 + wrow * 64 + mi * 16 + fq * 4;
#pragma unroll
      for (int q = 0; q < 4; ++q) {
        const int m = mb + q;
        const float vr = (accR[mi][ni][q] + bR) * scale;
        const float vi = (accI[mi][ni][q] + bI) * scale;
        const int s = m >> 2, b = m & 3;     // m = s*B + b
        const size_t o = (((size_t)(b * H_CNT + h) * S_LEN) + s) * D_HD + d;
        yr[o] = f2bf(vr); yi[o] = f2bf(vi);
      }
    }
  }
}

// ---------------------------------------------------------------------------
// MFMA complex flash attention, split softmax, no max tracking.
// Q pre-scaled by 0.125*log2(e) -> P = exp2(S) directly.
// 8-WAVE BLOCKS (512 thr): 128 q-rows share each K/V stage (2x amortization
// of staging + barrier drain vs the 4-wave version).  Per-wave state is
// byte-identical to the proven 84-VGPR 16-row kernel (no spill risk).
// Waves 0-3 stage K/V (same buffer ownership); waves 4-7 only consume.
// grid 512; XCD-resident remap: xcd = id&7 owns bh in [8*xcd, 8*xcd+8).
// SWAPPED QK^T: S = mfma(K_frag, Q_frag); q = lane&15, k per-lane contiguous.
// LDS: sK 16K + sVt 16K + sP 32K = 64KB -> 2 blocks/CU = 16 waves/CU.
// ---------------------------------------------------------------------------
__global__ __launch_bounds__(512, 2) void cattn_mfma(
    const ushort* __restrict__ Qr, const ushort* __restrict__ Qi,
    const ushort* __restrict__ Kr, const ushort* __restrict__ Ki,
    const ushort* __restrict__ Vtr, const ushort* __restrict__ Vti,
    ushort* __restrict__ AOr, ushort* __restrict__ AOi)
{
  __shared__ __align__(16) ushort sK[2][64][64];    // 16KB
  __shared__ __align__(16) ushort sVt[2][64][64];   // 16KB
  __shared__ __align__(16) ushort sP[8][2][16][64]; // 32KB

  const int tid  = threadIdx.x;
  const int lane = tid & 63;
  const int w    = tid >> 6;           // 0..7
  const int g    = lane >> 4;
  const int fr   = lane & 15;

  // XCD-resident bh mapping (bijective over 512 ids)
  const int id   = blockIdx.x;
  const int xcd  = id & 7;
  const int loc  = id >> 3;            // 0..63
  const int bh   = (xcd << 3) | (loc & 7);
  const int q0   = (loc >> 3) << 7;    // 8 q-tiles of 128
  const int b    = bh >> 4, h = bh & 15;
  const int qw   = q0 + 16 * w;        // 8 waves x 16 rows = 128

  // Q fragments: row qw+fr, d-slices kk*32 + g*8 (B operand: col=q)
  short8 qfr[2], qfi[2];
  const size_t qrow = ((size_t)bh * S_LEN + qw + fr) * D_HD;
#pragma unroll
  for (int kk = 0; kk < 2; ++kk) {
    qfr[kk] = *(const short8*)(Qr + qrow + kk * 32 + g * 8);
    qfi[kk] = *(const short8*)(Qi + qrow + kk * 32 + g * 8);
  }

  // staging: waves 0-3 own one buffer each; lane fetches pre-swizzled chunk
  const int lrow8 = lane >> 3;          // row offset within 8-row group
  const int sch   = (lane & 7) ^ lrow8; // source chunk (involution)
  const ushort* gsrc = nullptr; ushort* sdst = nullptr;
  if      (w == 0) { gsrc = Kr  + (size_t)bh * S_LEN * D_HD; sdst = &sK[0][0][0]; }
  else if (w == 1) { gsrc = Ki  + (size_t)bh * S_LEN * D_HD; sdst = &sK[1][0][0]; }
  else if (w == 2) { gsrc = Vtr + (size_t)bh * D_HD * S_LEN; sdst = &sVt[0][0][0]; }
  else if (w == 3) { gsrc = Vti + (size_t)bh * D_HD * S_LEN; sdst = &sVt[1][0][0]; }
  const bool isK = (w < 2);
  const bool stager = (w < 4);

  f32x4 accA[4] = {}, accAi[4] = {}, accB[4] = {}, accBi[4] = {};
  float lpr = 0.f, lpi = 0.f;   // per-lane partial denominators for q-row fr

  ushort* pR = &sP[w][0][0][0];
  ushort* pI = &sP[w][1][0][0];

  for (int kt = 0; kt < 16; ++kt) {
    __syncthreads();   // prev tile fully consumed by all waves
    if (stager) {
      if (isK) {
        const ushort* gp = gsrc + (size_t)kt * 4096 + lrow8 * 64 + sch * 8;
#pragma unroll
        for (int i = 0; i < 8; ++i)
          gld16(gp + i * 512, (char*)sdst + i * 1024);
      } else {
        const ushort* gp = gsrc + (size_t)lrow8 * S_LEN + kt * 64 + sch * 8;
#pragma unroll
        for (int i = 0; i < 8; ++i)
          gld16(gp + (size_t)i * 8 * S_LEN, (char*)sdst + i * 1024);
      }
    }
    __syncthreads();   // vmcnt drained by barrier: tiles ready

    // ---- QK^T (swapped: A = K block, B = Q) -> S[q=fr][k=16n+g*4+t] ----
    f32x4 Sr[4] = {}, Si[4] = {};
#pragma unroll
    for (int n = 0; n < 4; ++n) {
      const int kc = fr + 16 * n;              // A-fragment row = k-column
      const int rb = kc * 128, sw = (kc & 7) << 4;
#pragma unroll
      for (int kk = 0; kk < 2; ++kk) {
        const int off = rb + ((((kk * 4 + g) << 4)) ^ sw);
        short8 krf = *(const short8*)((const char*)&sK[0][0][0] + off);
        short8 kif = *(const short8*)((const char*)&sK[1][0][0] + off);
        short8 kin = kif ^ (short)0x8000;
        Sr[n] = mfma16(krf, qfr[kk], Sr[n]);
        Sr[n] = mfma16(kin, qfi[kk], Sr[n]);
        Si[n] = mfma16(kif, qfr[kk], Si[n]);
        Si[n] = mfma16(krf, qfi[kk], Si[n]);
      }
    }

    // ---- softmax numerators (exp2) + in-lane packed P write (b64) ----
    const int pbase = fr * 128 + ((g & 1) << 3);
#pragma unroll
    for (int n = 0; n < 4; ++n) {
      float p0 = __builtin_amdgcn_exp2f(Sr[n][0]);
      float p1 = __builtin_amdgcn_exp2f(Sr[n][1]);
      float p2 = __builtin_amdgcn_exp2f(Sr[n][2]);
      float p3 = __builtin_amdgcn_exp2f(Sr[n][3]);
      float q0_ = __builtin_amdgcn_exp2f(Si[n][0]);
      float q1_ = __builtin_amdgcn_exp2f(Si[n][1]);
      float q2_ = __builtin_amdgcn_exp2f(Si[n][2]);
      float q3_ = __builtin_amdgcn_exp2f(Si[n][3]);
      lpr += (p0 + p1) + (p2 + p3);
      lpi += (q0_ + q1_) + (q2_ + q3_);
      uint32_t a0, a1, b0, b1;
      asm("v_cvt_pk_bf16_f32 %0, %1, %2" : "=v"(a0) : "v"(p0), "v"(p1));
      asm("v_cvt_pk_bf16_f32 %0, %1, %2" : "=v"(a1) : "v"(p2), "v"(p3));
      asm("v_cvt_pk_bf16_f32 %0, %1, %2" : "=v"(b0) : "v"(q0_), "v"(q1_));
      asm("v_cvt_pk_bf16_f32 %0, %1, %2" : "=v"(b1) : "v"(q2_), "v"(q3_));
      const int chunk = (2 * n + (g >> 1)) ^ (fr & 7);
      const int off = pbase + (chunk << 4);
      uint2 pa; pa.x = a0; pa.y = a1;
      uint2 pb; pb.x = b0; pb.y = b1;
      *(uint2*)((char*)pR + off) = pa;
      *(uint2*)((char*)pI + off) = pb;
    }
    asm volatile("s_waitcnt lgkmcnt(0)" ::: "memory");  // own-wave P visible

    // ---- PV ----
    short8 prf[2], pif[2];
#pragma unroll
    for (int kk = 0; kk < 2; ++kk) {
      const int off = fr * 128 + ((((kk * 4 + g) << 4)) ^ ((fr & 7) << 4));
      prf[kk] = *(const short8*)((const char*)pR + off);
      pif[kk] = *(const short8*)((const char*)pI + off);
    }
#pragma unroll
    for (int n = 0; n < 4; ++n) {
      const int d = fr + 16 * n;
      const int rb = d * 128, sw = (d & 7) << 4;
#pragma unroll
      for (int kk = 0; kk < 2; ++kk) {
        const int off = rb + ((((kk * 4 + g) << 4)) ^ sw);
        short8 vrf = *(const short8*)((const char*)&sVt[0][0][0] + off);
        short8 vif = *(const short8*)((const char*)&sVt[1][0][0] + off);
        accA [n] = mfma16(prf[kk], vrf, accA [n]);
        accAi[n] = mfma16(prf[kk], vif, accAi[n]);
        accB [n] = mfma16(pif[kk], vrf, accB [n]);
        accBi[n] = mfma16(pif[kk], vif, accBi[n]);
      }
    }
  }

  // ---- final denominator reduce + transpose to epilogue row-indexing ----
  lpr += __shfl_xor(lpr, 16); lpr += __shfl_xor(lpr, 32);
  lpi += __shfl_xor(lpi, 16); lpi += __shfl_xor(lpi, 32);
  f32x4 ilr, ili;
#pragma unroll
  for (int t = 0; t < 4; ++t) {
    const int src = (lane & 48) + (g << 2) + t;   // lane holding row g*4+t
    ilr[t] = 1.f / __shfl(lpr, src, 64);
    ili[t] = 1.f / __shfl(lpi, src, 64);
  }

  // ---- epilogue ----
#pragma unroll
  for (int n = 0; n < 4; ++n) {
    const int e = h * 64 + fr + 16 * n;
#pragma unroll
    for (int t = 0; t < 4; ++t) {
      const int sidx = qw + g * 4 + t;
      const size_t o = ((size_t)b * S_LEN + sidx) * E_SZ + e;
      AOr[o] = f2bf(accA [n][t] * ilr[t] - accBi[n][t] * ili[t]);
      AOi[o] = f2bf(accAi[n][t] * ilr[t] + accB [n][t] * ili[t]);
    }
  }
}

extern "C" void kernel_launch(void* const* d_in, const int* in_sizes, int n_in,
                              void* d_out, int out_size, void* d_ws, size_t ws_size,
                              hipStream_t stream)
{
    const float* query_r = (const float*)d_in[0];
    const float* query_i = (const float*)d_in[1];
    const float* key_r   = (const float*)d_in[2];
    const float* key_i   = (const float*)d_in[3];
    const float* value_r = (const float*)d_in[4];
    const float* value_i = (const float*)d_in[5];
    const float* wq_r = (const float*)d_in[6];
    const float* wq_i = (const float*)d_in[7];
    const float* bq_r = (const float*)d_in[8];
    const float* bq_i = (const float*)d_in[9];
    const float* wk_r = (const float*)d_in[10];
    const float* wk_i = (const float*)d_in[11];
    const float* bk_r = (const float*)d_in[12];
    const float* bk_i = (const float*)d_in[13];
    const float* wv_r = (const float*)d_in[14];
    const float* wv_i = (const float*)d_in[15];
    const float* bv_r = (const float*)d_in[16];
    const float* bv_i = (const float*)d_in[17];
    const float* wo_r = (const float*)d_in[18];
    const float* wo_i = (const float*)d_in[19];
    const float* bo_r = (const float*)d_in[20];
    const float* bo_i = (const float*)d_in[21];

    // ws: Q(2) K(2) Vt(2) [bf16 N1 each] | weights 8*WELEM bf16 | AO(2)  = 80 MiB
    ushort* ws   = (ushort*)d_ws;
    ushort* Qr   = ws;
    ushort* Qi   = Qr + (size_t)N1;
    ushort* Kr   = Qi + (size_t)N1;
    ushort* Ki   = Kr + (size_t)N1;
    ushort* Vtr  = Ki + (size_t)N1;
    ushort* Vti  = Vtr + (size_t)N1;
    ushort* Wb   = Vti + (size_t)N1;
    ushort* Wq_r = Wb + 0 * (size_t)WELEM;
    ushort* Wq_i = Wb + 1 * (size_t)WELEM;
    ushort* Wk_r = Wb + 2 * (size_t)WELEM;
    ushort* Wk_i = Wb + 3 * (size_t)WELEM;
    ushort* Wv_r = Wb + 4 * (size_t)WELEM;
    ushort* Wv_i = Wb + 5 * (size_t)WELEM;
    ushort* Wo_r = Wb + 6 * (size_t)WELEM;
    ushort* Wo_i = Wb + 7 * (size_t)WELEM;
    ushort* AOr  = Wb + 8 * (size_t)WELEM;
    ushort* AOi  = AOr + (size_t)N1;

    // bf16 activation staging: Q/K pairs in d_out (32 MB of 33.5),
    // V pair in the AO slots (free until cattn; consumed by gemm-V first).
    ushort* Xq_r = (ushort*)d_out;
    ushort* Xq_i = Xq_r + (size_t)N1;
    ushort* Xk_r = Xq_i + (size_t)N1;
    ushort* Xk_i = Xk_r + (size_t)N1;
    ushort* Xv_r = AOr;
    ushort* Xv_i = AOi;

    cast_all<<<14336, 256, 0, stream>>>(
        wq_r, wq_i, wk_r, wk_i, wv_r, wv_i, wo_r, wo_i, Wb,
        query_r, query_i, key_r, key_i, value_r, value_i,
        Xq_r, Xq_i, Xk_r, Xk_i, Xv_r, Xv_i);

    // Q scale folds 1/sqrt(D)=0.125 AND log2(e) so attention uses exp2.
    cgemm_qk<<<1024, 256, 0, stream>>>(
        Xq_r, Xq_i, Xk_r, Xk_i,
        Wq_r, Wq_i, Wk_r, Wk_i,
        bq_r, bq_i, bk_r, bk_i,
        Qr, Qi, Kr, Ki,
        0.18033688011112043f);

    dim3 gg(16, 32);   // 512 workgroups, BN=64, BM=128
    cgemm<1><<<gg, 256, 0, stream>>>(Xv_r, Xv_i, Wv_r, Wv_i, bv_r, bv_i,
                                     Vtr, Vti, nullptr, 1.0f);

    cattn_mfma<<<512, 512, 0, stream>>>(
        Qr, Qi, Kr, Ki, Vtr, Vti, AOr, AOi);

    cgemm<2><<<gg, 256, 0, stream>>>(
        AOr, AOi, Wo_r, Wo_i, bo_r, bo_i, nullptr, nullptr, (float*)d_out, 1.0f);
}

// Round 16
// 261.912 us; speedup vs baseline: 1.0619x; 1.0619x over previous
//
#include <hip/hip_runtime.h>
#include <hip/hip_bf16.h>
#include <stdint.h>

#define S_LEN 1024
#define B_SZ  4
#define E_SZ  1024
#define H_CNT 16
#define D_HD  64
#define N1    (B_SZ * H_CNT * S_LEN * D_HD)   // 4194304 elements per component
#define WELEM (E_SZ * E_SZ)                   // 1048576

typedef __attribute__((ext_vector_type(8))) short short8;
typedef __attribute__((ext_vector_type(4))) float f32x4;

__device__ __forceinline__ ushort f2bf(float f) {
  union { float f; uint32_t u; } v; v.f = f;
  uint32_t u = v.u;
  uint32_t r = (u + 0x7fffu + ((u >> 16) & 1u)) >> 16;  // RNE
  return (ushort)r;
}
__device__ __forceinline__ short8 pack8(float4 a, float4 b) {
  short8 r;
  r[0] = (short)f2bf(a.x); r[1] = (short)f2bf(a.y);
  r[2] = (short)f2bf(a.z); r[3] = (short)f2bf(a.w);
  r[4] = (short)f2bf(b.x); r[5] = (short)f2bf(b.y);
  r[6] = (short)f2bf(b.z); r[7] = (short)f2bf(b.w);
  return r;
}
static __device__ __forceinline__ f32x4 mfma16(short8 a, short8 b, f32x4 c) {
  return __builtin_amdgcn_mfma_f32_16x16x32_bf16(a, b, c, 0, 0, 0);
}

typedef const __attribute__((address_space(1))) void gv_t;
typedef __attribute__((address_space(3))) void lv_t;
__device__ __forceinline__ void gld16(const void* g, void* l) {
  __builtin_amdgcn_global_load_lds((gv_t*)g, (lv_t*)l, 16, 0, 0);
}

// ---------------------------------------------------------------------------
// Fused cast kernel: 8 weight matrices (4 el/thread) + 3 activation pairs
// (8 el/thread).  blocks [0,8192) = weights; [8192,14336) = activations.
// ---------------------------------------------------------------------------
__global__ __launch_bounds__(256) void cast_all(
    const float* __restrict__ s0, const float* __restrict__ s1,
    const float* __restrict__ s2, const float* __restrict__ s3,
    const float* __restrict__ s4, const float* __restrict__ s5,
    const float* __restrict__ s6, const float* __restrict__ s7,
    ushort* __restrict__ wdst,
    const float* __restrict__ qr, const float* __restrict__ qi,
    const float* __restrict__ kr, const float* __restrict__ ki,
    const float* __restrict__ vr, const float* __restrict__ vi,
    ushort* __restrict__ xq_r, ushort* __restrict__ xq_i,
    ushort* __restrict__ xk_r, ushort* __restrict__ xk_i,
    ushort* __restrict__ xv_r, ushort* __restrict__ xv_i)
{
  int blk = blockIdx.x;
  if (blk < 8192) {
    const size_t i = (size_t)blk * 256 + threadIdx.x;
    const size_t e = i * 4;
    const int which = (int)(e >> 20);
    const size_t off = e & (WELEM - 1);
    const float* s = which < 4
        ? (which < 2 ? (which == 0 ? s0 : s1) : (which == 2 ? s2 : s3))
        : (which < 6 ? (which == 4 ? s4 : s5) : (which == 6 ? s6 : s7));
    const float4 f = *(const float4*)(s + off);
    ushort4 u;
    u.x = f2bf(f.x); u.y = f2bf(f.y); u.z = f2bf(f.z); u.w = f2bf(f.w);
    *(ushort4*)(wdst + e) = u;
    return;
  }
  blk -= 8192;
  const float *xr, *xi; ushort *yr, *yi;
  if      (blk < 2048) { xr = qr; xi = qi; yr = xq_r; yi = xq_i; }
  else if (blk < 4096) { xr = kr; xi = ki; yr = xk_r; yi = xk_i; blk -= 2048; }
  else                 { xr = vr; xi = vi; yr = xv_r; yi = xv_i; blk -= 4096; }
  const size_t e = ((size_t)blk * 256 + threadIdx.x) * 8;
  float4 a = *(const float4*)(xr + e);
  float4 b = *(const float4*)(xr + e + 4);
  *(short8*)(yr + e) = pack8(a, b);
  a = *(const float4*)(xi + e);
  b = *(const float4*)(xi + e + 4);
  *(short8*)(yi + e) = pack8(a, b);
}

// ---------------------------------------------------------------------------
// Unified complex bf16 MFMA GEMM:  Y = (A @ W^T + bias) * scale
// Tile BM=128 x BN=64, BK=64; 256 threads = 4 waves (2x2), wave tile 64x32.
// MODE 0: out bf16 [B,H,S,D]; MODE 1: out bf16 [B,H,D,S]; MODE 2: fp32 [S,B,E,2]
// ---------------------------------------------------------------------------
template<int MODE>
__global__ __launch_bounds__(256) void cgemm(
    const ushort* __restrict__ ar_, const ushort* __restrict__ ai_,
    const ushort* __restrict__ wre, const ushort* __restrict__ wim,
    const float* __restrict__ bre, const float* __restrict__ bim,
    ushort* __restrict__ yr, ushort* __restrict__ yi,
    float* __restrict__ outf, float scale)
{
  __shared__ __align__(16) ushort sAr[128 * 64], sAi[128 * 64];
  __shared__ __align__(16) ushort sBr[64 * 64],  sBi[64 * 64];

  const int tid  = threadIdx.x;
  const int lane = tid & 63;
  const int w    = tid >> 6;
  const int wrow = w >> 1, wcol = w & 1;
  const int fr   = lane & 15, fq = lane >> 4;

  // bijective XCD swizzle over 512 workgroups (512 % 8 == 0)
  const int flat = blockIdx.x + gridDim.x * blockIdx.y;
  const int swz  = (flat & 7) * 64 + (flat >> 3);
  const int n0   = (swz & 15) * 64;    // 16 n-tiles of 64
  const int m0   = (swz >> 4) * 128;   // 32 m-tiles of 128

  const ushort* gbase = (w == 0) ? ar_ : (w == 1) ? ai_ : (w == 2) ? wre : wim;
  char* sbase = (w == 0) ? (char*)sAr : (w == 1) ? (char*)sAi
              : (w == 2) ? (char*)sBr : (char*)sBi;
  const int rbase = (w < 2) ? m0 : n0;
  const int lrow  = lane >> 3;            // 0..7
  const int sch   = (lane & 7) ^ lrow;    // pre-swizzled source chunk
  const ushort* gp0 = gbase + (size_t)(rbase + lrow) * E_SZ + sch * 8;

  f32x4 accR[4][2] = {}, accI[4][2] = {};

  for (int kt = 0; kt < 16; ++kt) {
    const int k0 = kt * 64;
    __syncthreads();   // previous tile fully consumed
    if (w < 2) {
#pragma unroll
      for (int i = 0; i < 16; ++i)
        gld16(gp0 + (size_t)i * 8 * E_SZ + k0, sbase + i * 1024);
    } else {
#pragma unroll
      for (int i = 0; i < 8; ++i)
        gld16(gp0 + (size_t)i * 8 * E_SZ + k0, sbase + i * 1024);
    }
    __syncthreads();   // vmcnt drained by barrier: tile ready

#pragma unroll
    for (int kk = 0; kk < 2; ++kk) {
      short8 a_r[4], a_i[4], a_n[4], b_r[2], b_i[2];
#pragma unroll
      for (int mi = 0; mi < 4; ++mi) {
        const int row = wrow * 64 + mi * 16 + fr;
        const int off = row * 128 + (((kk * 4 + fq) ^ (row & 7)) << 4);
        a_r[mi] = *(const short8*)((const char*)sAr + off);
        a_i[mi] = *(const short8*)((const char*)sAi + off);
        a_n[mi] = a_i[mi] ^ (short)0x8000;
      }
#pragma unroll
      for (int ni = 0; ni < 2; ++ni) {
        const int row = wcol * 32 + ni * 16 + fr;
        const int off = row * 128 + (((kk * 4 + fq) ^ (row & 7)) << 4);
        b_r[ni] = *(const short8*)((const char*)sBr + off);
        b_i[ni] = *(const short8*)((const char*)sBi + off);
      }
      __builtin_amdgcn_s_setprio(1);
#pragma unroll
      for (int mi = 0; mi < 4; ++mi)
#pragma unroll
        for (int ni = 0; ni < 2; ++ni) {
          accR[mi][ni] = mfma16(a_r[mi], b_r[ni], accR[mi][ni]);
          accR[mi][ni] = mfma16(a_n[mi], b_i[ni], accR[mi][ni]);
          accI[mi][ni] = mfma16(a_r[mi], b_i[ni], accI[mi][ni]);
          accI[mi][ni] = mfma16(a_i[mi], b_r[ni], accI[mi][ni]);
        }
      __builtin_amdgcn_s_setprio(0);
    }
  }

  // epilogue: C/D layout col=lane&15, row=(lane>>4)*4+reg
#pragma unroll
  for (int ni = 0; ni < 2; ++ni) {
    const int n = n0 + wcol * 32 + ni * 16 + fr;
    const float bR = bre[n], bI = bim[n];
    const int h = n >> 6, d = n & 63;
#pragma unroll
    for (int mi = 0; mi < 4; ++mi) {
      const int mb = m0 + wrow * 64 + mi * 16 + fq * 4;
#pragma unroll
      for (int q = 0; q < 4; ++q) {
        const int m = mb + q;
        const float vr = (accR[mi][ni][q] + bR) * scale;
        const float vi = (accI[mi][ni][q] + bI) * scale;
        if (MODE == 0) {
          const int s = m >> 2, b = m & 3;   // m = s*B + b
          const size_t o = (((size_t)(b * H_CNT + h) * S_LEN) + s) * D_HD + d;
          yr[o] = f2bf(vr); yi[o] = f2bf(vi);
        } else if (MODE == 1) {
          const int s = m >> 2, b = m & 3;
          const size_t o = (((size_t)(b * H_CNT + h) * D_HD) + d) * S_LEN + s;
          yr[o] = f2bf(vr); yi[o] = f2bf(vi);
        } else {
          const int b = m >> 10, s = m & 1023;  // m = b*S + s
          const size_t o = (((size_t)(s * B_SZ + b) * E_SZ) + n) * 2;
          outf[o] = vr; outf[o + 1] = vi;
        }
      }
    }
  }
}

// ---------------------------------------------------------------------------
// MFMA complex flash attention, split softmax, no max tracking.
// Q pre-scaled by 0.125*log2(e) -> P = exp2(S) directly.
// grid 1024 linear; XCD-resident remap: xcd = id&7 owns bh in [8*xcd, 8*xcd+8).
// SWAPPED QK^T: S = mfma(K_frag, Q_frag); q = lane&15, k per-lane contiguous.
// This is the empirically best cattn (round-12 config: 4 waves, 16 q-rows
// per wave, separate sP, 48KB LDS, launch_bounds(256,3), gld_lds staging):
// measured 88.2-88.8 us across three rounds, zero spill.
// Rejected by measurement: T14 reg-staging (spill, 2.4x), phase-split
// prefetch (-8%), P-aliased LDS squeeze (neutral), 8-wave blocks (-7%),
// (256,4) occupancy forcing (spill, 1.7x).
// ---------------------------------------------------------------------------
__global__ __launch_bounds__(256, 3) void cattn_mfma(
    const ushort* __restrict__ Qr, const ushort* __restrict__ Qi,
    const ushort* __restrict__ Kr, const ushort* __restrict__ Ki,
    const ushort* __restrict__ Vtr, const ushort* __restrict__ Vti,
    ushort* __restrict__ AOr, ushort* __restrict__ AOi)
{
  __shared__ __align__(16) ushort sK[2][64][64];    // 16KB
  __shared__ __align__(16) ushort sVt[2][64][64];   // 16KB
  __shared__ __align__(16) ushort sP[4][2][16][64]; // 16KB

  const int tid  = threadIdx.x;
  const int lane = tid & 63;
  const int w    = tid >> 6;
  const int g    = lane >> 4;
  const int fr   = lane & 15;

  // XCD-resident bh mapping (bijective over 1024 ids)
  const int id   = blockIdx.x;
  const int xcd  = id & 7;
  const int loc  = id >> 3;            // 0..127
  const int bh   = (xcd << 3) | (loc & 7);
  const int q0   = (loc >> 3) << 6;    // 16 q-tiles of 64
  const int b    = bh >> 4, h = bh & 15;
  const int qw   = q0 + 16 * w;

  // Q fragments: row qw+fr, d-slices kk*32 + g*8 (B operand: col=q)
  short8 qfr[2], qfi[2];
  const size_t qrow = ((size_t)bh * S_LEN + qw + fr) * D_HD;
#pragma unroll
  for (int kk = 0; kk < 2; ++kk) {
    qfr[kk] = *(const short8*)(Qr + qrow + kk * 32 + g * 8);
    qfi[kk] = *(const short8*)(Qi + qrow + kk * 32 + g * 8);
  }

  // staging: wave w owns one buffer; lane fetches pre-swizzled global chunk
  const int lrow8 = lane >> 3;          // row offset within 8-row group
  const int sch   = (lane & 7) ^ lrow8; // source chunk (involution)
  const ushort* gsrc; ushort* sdst;
  if      (w == 0) { gsrc = Kr  + (size_t)bh * S_LEN * D_HD; sdst = &sK[0][0][0]; }
  else if (w == 1) { gsrc = Ki  + (size_t)bh * S_LEN * D_HD; sdst = &sK[1][0][0]; }
  else if (w == 2) { gsrc = Vtr + (size_t)bh * D_HD * S_LEN; sdst = &sVt[0][0][0]; }
  else             { gsrc = Vti + (size_t)bh * D_HD * S_LEN; sdst = &sVt[1][0][0]; }
  const bool isK = (w < 2);

  f32x4 accA[4] = {}, accAi[4] = {}, accB[4] = {}, accBi[4] = {};
  float lpr = 0.f, lpi = 0.f;   // per-lane partial denominators for q-row fr

  ushort* pR = &sP[w][0][0][0];
  ushort* pI = &sP[w][1][0][0];

  for (int kt = 0; kt < 16; ++kt) {
    __syncthreads();   // prev tile fully consumed by all waves
    if (isK) {
      const ushort* gp = gsrc + (size_t)kt * 4096 + lrow8 * 64 + sch * 8;
#pragma unroll
      for (int i = 0; i < 8; ++i)
        gld16(gp + i * 512, (char*)sdst + i * 1024);
    } else {
      const ushort* gp = gsrc + (size_t)lrow8 * S_LEN + kt * 64 + sch * 8;
#pragma unroll
      for (int i = 0; i < 8; ++i)
        gld16(gp + (size_t)i * 8 * S_LEN, (char*)sdst + i * 1024);
    }
    __syncthreads();   // vmcnt drained by barrier: tile ready

    // ---- QK^T (swapped: A = K block, B = Q) -> S[q=fr][k=16n+g*4+t] ----
    f32x4 Sr[4] = {}, Si[4] = {};
#pragma unroll
    for (int n = 0; n < 4; ++n) {
      const int kc = fr + 16 * n;              // A-fragment row = k-column
      const int rb = kc * 128, sw = (kc & 7) << 4;
#pragma unroll
      for (int kk = 0; kk < 2; ++kk) {
        const int off = rb + ((((kk * 4 + g) << 4)) ^ sw);
        short8 krf = *(const short8*)((const char*)&sK[0][0][0] + off);
        short8 kif = *(const short8*)((const char*)&sK[1][0][0] + off);
        short8 kin = kif ^ (short)0x8000;
        Sr[n] = mfma16(krf, qfr[kk], Sr[n]);
        Sr[n] = mfma16(kin, qfi[kk], Sr[n]);
        Si[n] = mfma16(kif, qfr[kk], Si[n]);
        Si[n] = mfma16(krf, qfi[kk], Si[n]);
      }
    }

    // ---- softmax numerators (exp2) + in-lane packed P write (b64) ----
    const int pbase = fr * 128 + ((g & 1) << 3);
#pragma unroll
    for (int n = 0; n < 4; ++n) {
      float p0 = __builtin_amdgcn_exp2f(Sr[n][0]);
      float p1 = __builtin_amdgcn_exp2f(Sr[n][1]);
      float p2 = __builtin_amdgcn_exp2f(Sr[n][2]);
      float p3 = __builtin_amdgcn_exp2f(Sr[n][3]);
      float q0_ = __builtin_amdgcn_exp2f(Si[n][0]);
      float q1_ = __builtin_amdgcn_exp2f(Si[n][1]);
      float q2_ = __builtin_amdgcn_exp2f(Si[n][2]);
      float q3_ = __builtin_amdgcn_exp2f(Si[n][3]);
      lpr += (p0 + p1) + (p2 + p3);
      lpi += (q0_ + q1_) + (q2_ + q3_);
      uint32_t a0, a1, b0, b1;
      asm("v_cvt_pk_bf16_f32 %0, %1, %2" : "=v"(a0) : "v"(p0), "v"(p1));
      asm("v_cvt_pk_bf16_f32 %0, %1, %2" : "=v"(a1) : "v"(p2), "v"(p3));
      asm("v_cvt_pk_bf16_f32 %0, %1, %2" : "=v"(b0) : "v"(q0_), "v"(q1_));
      asm("v_cvt_pk_bf16_f32 %0, %1, %2" : "=v"(b1) : "v"(q2_), "v"(q3_));
      const int chunk = (2 * n + (g >> 1)) ^ (fr & 7);
      const int off = pbase + (chunk << 4);
      uint2 pa; pa.x = a0; pa.y = a1;
      uint2 pb; pb.x = b0; pb.y = b1;
      *(uint2*)((char*)pR + off) = pa;
      *(uint2*)((char*)pI + off) = pb;
    }
    asm volatile("s_waitcnt lgkmcnt(0)" ::: "memory");

    // ---- PV ----
    short8 prf[2], pif[2];
#pragma unroll
    for (int kk = 0; kk < 2; ++kk) {
      const int off = fr * 128 + ((((kk * 4 + g) << 4)) ^ ((fr & 7) << 4));
      prf[kk] = *(const short8*)((const char*)pR + off);
      pif[kk] = *(const short8*)((const char*)pI + off);
    }
#pragma unroll
    for (int n = 0; n < 4; ++n) {
      const int d = fr + 16 * n;
      const int rb = d * 128, sw = (d & 7) << 4;
#pragma unroll
      for (int kk = 0; kk < 2; ++kk) {
        const int off = rb + ((((kk * 4 + g) << 4)) ^ sw);
        short8 vrf = *(const short8*)((const char*)&sVt[0][0][0] + off);
        short8 vif = *(const short8*)((const char*)&sVt[1][0][0] + off);
        accA [n] = mfma16(prf[kk], vrf, accA [n]);
        accAi[n] = mfma16(prf[kk], vif, accAi[n]);
        accB [n] = mfma16(pif[kk], vrf, accB [n]);
        accBi[n] = mfma16(pif[kk], vif, accBi[n]);
      }
    }
  }

  // ---- final denominator reduce + transpose to epilogue row-indexing ----
  lpr += __shfl_xor(lpr, 16); lpr += __shfl_xor(lpr, 32);
  lpi += __shfl_xor(lpi, 16); lpi += __shfl_xor(lpi, 32);
  f32x4 ilr, ili;
#pragma unroll
  for (int t = 0; t < 4; ++t) {
    const int src = (lane & 48) + (g << 2) + t;   // lane holding row g*4+t
    ilr[t] = 1.f / __shfl(lpr, src, 64);
    ili[t] = 1.f / __shfl(lpi, src, 64);
  }

  // ---- epilogue ----
#pragma unroll
  for (int n = 0; n < 4; ++n) {
    const int e = h * 64 + fr + 16 * n;
#pragma unroll
    for (int t = 0; t < 4; ++t) {
      const int sidx = qw + g * 4 + t;
      const size_t o = ((size_t)b * S_LEN + sidx) * E_SZ + e;
      AOr[o] = f2bf(accA [n][t] * ilr[t] - accBi[n][t] * ili[t]);
      AOi[o] = f2bf(accAi[n][t] * ilr[t] + accB [n][t] * ili[t]);
    }
  }
}

extern "C" void kernel_launch(void* const* d_in, const int* in_sizes, int n_in,
                              void* d_out, int out_size, void* d_ws, size_t ws_size,
                              hipStream_t stream)
{
    const float* query_r = (const float*)d_in[0];
    const float* query_i = (const float*)d_in[1];
    const float* key_r   = (const float*)d_in[2];
    const float* key_i   = (const float*)d_in[3];
    const float* value_r = (const float*)d_in[4];
    const float* value_i = (const float*)d_in[5];
    const float* wq_r = (const float*)d_in[6];
    const float* wq_i = (const float*)d_in[7];
    const float* bq_r = (const float*)d_in[8];
    const float* bq_i = (const float*)d_in[9];
    const float* wk_r = (const float*)d_in[10];
    const float* wk_i = (const float*)d_in[11];
    const float* bk_r = (const float*)d_in[12];
    const float* bk_i = (const float*)d_in[13];
    const float* wv_r = (const float*)d_in[14];
    const float* wv_i = (const float*)d_in[15];
    const float* bv_r = (const float*)d_in[16];
    const float* bv_i = (const float*)d_in[17];
    const float* wo_r = (const float*)d_in[18];
    const float* wo_i = (const float*)d_in[19];
    const float* bo_r = (const float*)d_in[20];
    const float* bo_i = (const float*)d_in[21];

    // ws: Q(2) K(2) Vt(2) [bf16 N1 each] | weights 8*WELEM bf16 | AO(2)  = 80 MiB
    ushort* ws   = (ushort*)d_ws;
    ushort* Qr   = ws;
    ushort* Qi   = Qr + (size_t)N1;
    ushort* Kr   = Qi + (size_t)N1;
    ushort* Ki   = Kr + (size_t)N1;
    ushort* Vtr  = Ki + (size_t)N1;
    ushort* Vti  = Vtr + (size_t)N1;
    ushort* Wb   = Vti + (size_t)N1;
    ushort* Wq_r = Wb + 0 * (size_t)WELEM;
    ushort* Wq_i = Wb + 1 * (size_t)WELEM;
    ushort* Wk_r = Wb + 2 * (size_t)WELEM;
    ushort* Wk_i = Wb + 3 * (size_t)WELEM;
    ushort* Wv_r = Wb + 4 * (size_t)WELEM;
    ushort* Wv_i = Wb + 5 * (size_t)WELEM;
    ushort* Wo_r = Wb + 6 * (size_t)WELEM;
    ushort* Wo_i = Wb + 7 * (size_t)WELEM;
    ushort* AOr  = Wb + 8 * (size_t)WELEM;
    ushort* AOi  = AOr + (size_t)N1;

    // bf16 activation staging: Q/K pairs in d_out (32 MB of 33.5),
    // V pair in the AO slots (free until cattn; consumed by gemm-V first).
    ushort* Xq_r = (ushort*)d_out;
    ushort* Xq_i = Xq_r + (size_t)N1;
    ushort* Xk_r = Xq_i + (size_t)N1;
    ushort* Xk_i = Xk_r + (size_t)N1;
    ushort* Xv_r = AOr;
    ushort* Xv_i = AOi;

    cast_all<<<14336, 256, 0, stream>>>(
        wq_r, wq_i, wk_r, wk_i, wv_r, wv_i, wo_r, wo_i, Wb,
        query_r, query_i, key_r, key_i, value_r, value_i,
        Xq_r, Xq_i, Xk_r, Xk_i, Xv_r, Xv_i);

    dim3 gg(16, 32);   // 512 workgroups, BN=64, BM=128
    // Q scale folds 1/sqrt(D)=0.125 AND log2(e) so attention uses exp2.
    cgemm<0><<<gg, 256, 0, stream>>>(Xq_r, Xq_i, Wq_r, Wq_i, bq_r, bq_i,
                                     Qr, Qi, nullptr, 0.18033688011112043f);
    cgemm<0><<<gg, 256, 0, stream>>>(Xk_r, Xk_i, Wk_r, Wk_i, bk_r, bk_i,
                                     Kr, Ki, nullptr, 1.0f);
    cgemm<1><<<gg, 256, 0, stream>>>(Xv_r, Xv_i, Wv_r, Wv_i, bv_r, bv_i,
                                     Vtr, Vti, nullptr, 1.0f);

    cattn_mfma<<<1024, 256, 0, stream>>>(
        Qr, Qi, Kr, Ki, Vtr, Vti, AOr, AOi);

    cgemm<2><<<gg, 256, 0, stream>>>(
        AOr, AOi, Wo_r, Wo_i, bo_r, bo_i, nullptr, nullptr, (float*)d_out, 1.0f);
}